// Round 4
// baseline (388.111 us; speedup 1.0000x reference)
//
#include <hip/hip_runtime.h>
#include <stdint.h>

typedef _Float16 f16;
typedef _Float16 f16x8 __attribute__((ext_vector_type(8)));
typedef _Float16 f16x4 __attribute__((ext_vector_type(4)));
typedef _Float16 f16x2 __attribute__((ext_vector_type(2)));
typedef float f32x4 __attribute__((ext_vector_type(4)));

__device__ __forceinline__ f32x4 mfma16(f16x8 a, f16x8 b, f32x4 c) {
    return __builtin_amdgcn_mfma_f32_16x16x32_f16(a, b, c, 0, 0, 0);
}

// Async global->LDS, 16B per lane. LDS dest = wave-uniform base + lane*16.
__device__ __forceinline__ void gload16(const f16* g, f16* l) {
    __builtin_amdgcn_global_load_lds(
        (const __attribute__((address_space(1))) uint32_t*)g,
        (__attribute__((address_space(3))) uint32_t*)l, 16, 0, 0);
}

// ---------------------------------------------------------------------------
// Shared GEMM body: C[m][n] = (sum_k A[m*1024+k]*B[n*1024+k] + bias) * scale.
// K=1024. 128x128 tile, 4 waves 2x2, 16x16x32 f16 MFMA, global_load_lds
// staging with XOR chunk swizzle folded into per-lane source addresses.
// Round-0 structure (proven best): single 32KB LDS buffer -> 4 blocks/CU;
// inter-block TLP hides the stage->drain latency (round-1 dbuf at 64KB
// lost occupancy and regressed -8%).
// ---------------------------------------------------------------------------
template <bool OUT16>
__device__ __forceinline__ void gemm_body(const f16* __restrict__ A,
                                          const f16* __restrict__ B,
                                          const float* __restrict__ bias,
                                          void* __restrict__ Cout, long ldo,
                                          int biasrow, float scale,
                                          long m0, long n0, f16* As, f16* Bs) {
    int tid = threadIdx.x;
    int lane = tid & 63, w = tid >> 6;
    int wm = w & 1, wn = w >> 1;
    int l15 = lane & 15, quad = lane >> 4;

    int rg = lane >> 3;        // row within 8-row staging group
    int cg = (lane & 7) ^ rg;  // global chunk index (swizzled)
    const f16* ag[4];
    const f16* bg[4];
    f16* al[4];
    f16* bl[4];
#pragma unroll
    for (int t = 0; t < 4; ++t) {
        int rb = (w * 4 + t) * 8;
        ag[t] = A + (m0 + rb + rg) * 1024 + cg * 8;
        bg[t] = B + (n0 + rb + rg) * 1024 + cg * 8;
        al[t] = &As[rb * 64];
        bl[t] = &Bs[rb * 64];
    }

    f32x4 acc[4][4] = {};

    for (int k0 = 0; k0 < 1024; k0 += 64) {
        __syncthreads();
#pragma unroll
        for (int t = 0; t < 4; ++t) {
            gload16(ag[t] + k0, al[t]);
            gload16(bg[t] + k0, bl[t]);
        }
        __syncthreads();
#pragma unroll
        for (int ks = 0; ks < 2; ++ks) {
            int cc = (ks * 4 + quad) ^ (l15 & 7);
            f16x8 af[4], bf[4];
#pragma unroll
            for (int t = 0; t < 4; ++t) {
                af[t] = *(const f16x8*)&As[(wm * 64 + t * 16 + l15) * 64 + cc * 8];
                bf[t] = *(const f16x8*)&Bs[(wn * 64 + t * 16 + l15) * 64 + cc * 8];
            }
#pragma unroll
            for (int i = 0; i < 4; ++i)
#pragma unroll
                for (int j = 0; j < 4; ++j)
                    acc[i][j] = mfma16(af[i], bf[j], acc[i][j]);
        }
    }

    // C/D layout: col = lane&15, row = quad*4 + reg
#pragma unroll
    for (int i = 0; i < 4; ++i) {
        int mrow = wm * 64 + i * 16 + quad * 4;
#pragma unroll
        for (int j = 0; j < 4; ++j) {
            int ncol = wn * 64 + j * 16 + l15;
            long gn = n0 + ncol;
#pragma unroll
            for (int r = 0; r < 4; ++r) {
                long gm = m0 + mrow + r;
                float v = (acc[i][j][r] + (biasrow ? bias[gm] : bias[gn])) * scale;
                if constexpr (OUT16)
                    ((f16*)Cout)[gm * ldo + gn] = (f16)v;
                else
                    ((float*)Cout)[gm * ldo + gn] = v;
            }
        }
    }
}

// Merged Q/K/V projection: grid (64, 8, 3); z selects operand set.
// z=0: Qp = (q@Wq^T+bq)*log2e/32  (softmax scale folded -> attn uses exp2)
// z=1: Kp = k@Wk^T+bk
// z=2: Vt = (v@Wv^T+bv)^T  computed as Wv x v^T -> [e][tok], bias per row
__global__ __launch_bounds__(256, 2) void qkv_proj(
    const f16* __restrict__ qh, const f16* __restrict__ kh,
    const f16* __restrict__ vh, const f16* __restrict__ Wh,
    const float* __restrict__ bq, const float* __restrict__ bk,
    const float* __restrict__ bv, f16* __restrict__ Qp, f16* __restrict__ Kp,
    f16* __restrict__ Vt) {
    __shared__ __align__(16) f16 As[128 * 64];
    __shared__ __align__(16) f16 Bs[128 * 64];
    int z = blockIdx.z;
    const f16* A;
    const f16* B;
    const float* bias;
    f16* C;
    long ldo;
    int biasrow;
    float scale;
    if (z == 0) {
        A = qh; B = Wh; bias = bq; C = Qp; ldo = 1024; biasrow = 0;
        scale = 0.0450842200277786f;  // log2(e)/32
    } else if (z == 1) {
        A = kh; B = Wh + 1048576; bias = bk; C = Kp; ldo = 1024; biasrow = 0;
        scale = 1.0f;
    } else {
        A = Wh + 2097152; B = vh; bias = bv; C = Vt; ldo = 8192; biasrow = 1;
        scale = 1.0f;
    }
    long m0 = (long)(z == 2 ? blockIdx.y : blockIdx.x) * 128;
    long n0 = (long)(z == 2 ? blockIdx.x : blockIdx.y) * 128;
    gemm_body<true>(A, B, bias, C, ldo, biasrow, scale, m0, n0, As, Bs);
}

// Output projection: out = Op@Wo^T + bo (fp32 out)
__global__ __launch_bounds__(256, 2) void o_proj(const f16* __restrict__ Op,
                                                 const f16* __restrict__ Wo,
                                                 const float* __restrict__ bo,
                                                 float* __restrict__ out) {
    __shared__ __align__(16) f16 As[128 * 64];
    __shared__ __align__(16) f16 Bs[128 * 64];
    gemm_body<false>(Op, Wo, bo, out, 1024, 0, 1.0f, (long)blockIdx.x * 128,
                     (long)blockIdx.y * 128, As, Bs);
}

// ---------------------------------------------------------------------------
// Attention v6: BARRIER-FREE. One block per (n, h, 256-row q-PAIR); 512
// blocks = 2/CU, zero tail (v3 geometry). K/V per (n,h) is only 512 KB --
// L2-resident (XCD swizzle co-locates all 8 blocks of an (n,h) on one XCD).
// So: NO LDS staging of K/V, NO gload_lds, NO __syncthreads anywhere.
// K/V/Q fragments load straight from global (L2 hits); LDS holds only P
// (wave-private rows, XOR-swizzled) -- per-wave in-order DS needs no
// barriers. This removes the per-kt vmcnt(0)+lgkmcnt(0) block drain that
// phase-locked the waves (v3: MfmaUtil 31 + VALUBusy 39, ~30% dead).
// Waves free-run; compiler emits per-register s_waitcnt vmcnt(N).
// V-frag loads are issued between S and exp/pack so L2 latency hides
// under the exp VALU work. Unnormalized softmax (Qp pre-scaled by
// log2e/32 -> raw v_exp_f32).
// ---------------------------------------------------------------------------
__global__ __launch_bounds__(256, 2) void attn256(const f16* __restrict__ Qp,
                                                  const f16* __restrict__ Kp,
                                                  const f16* __restrict__ Vt,
                                                  f16* __restrict__ Op) {
    __shared__ __align__(16) f16 Ps0[128 * 64];
    __shared__ __align__(16) f16 Ps1[128 * 64];

    int tid = threadIdx.x;
    int lane = tid & 63, w = tid >> 6;
    int l15 = lane & 15, quad = lane >> 4;
    int b = blockIdx.x;
    int xcd = b & 7, slot = b >> 3;        // 64 slots per XCD
    int nh = xcd * 8 + (slot >> 3);        // 8 (n,h) per XCD
    int qp = slot & 7;                     // 8 q-pairs per (n,h)
    int nb = nh >> 4, h = nh & 15;
    long tok0 = (long)nb * 2048;
    long qrow0 = qp * 256;

    // Q fragments straight from global (one-time, 16 x 16B loads)
    // B-operand layout: lane l15 = q-row, elements = d in [ks*32+quad*8, +8)
    const f16* qbase = Qp + (tok0 + qrow0) * 1024 + h * 64;
    f16x8 qf0[2][2], qf1[2][2];
#pragma unroll
    for (int ks = 0; ks < 2; ++ks)
#pragma unroll
        for (int j = 0; j < 2; ++j) {
            long row = w * 32 + j * 16 + l15;
            qf0[ks][j] = *(const f16x8*)&qbase[row * 1024 + ks * 32 + quad * 8];
            qf1[ks][j] = *(const f16x8*)&qbase[(row + 128) * 1024 + ks * 32 + quad * 8];
        }

    f32x4 oacc0[2][4] = {}, oacc1[2][4] = {};
    float rs0[2] = {0.f, 0.f}, rs1[2] = {0.f, 0.f};
    const f32x4 z4 = {0.f, 0.f, 0.f, 0.f};

    // per-kt advancing base pointers
    const f16* kkt = Kp + tok0 * 1024 + h * 64;       // +64*1024 per kt
    const f16* vkt = Vt + ((long)h * 64) * 8192 + tok0;  // +64 per kt

    for (int kt = 0; kt < 32; ++kt) {
        // ---- S: K fragments from L2; A-operand lane l15 = k-token row ----
        f32x4 sacc0[4][2], sacc1[4][2];
        __builtin_amdgcn_s_setprio(1);
#pragma unroll
        for (int ks = 0; ks < 2; ++ks) {
            f16x8 a[4];
#pragma unroll
            for (int t = 0; t < 4; ++t)
                a[t] = *(const f16x8*)&kkt[(long)(t * 16 + l15) * 1024 + ks * 32 + quad * 8];
#pragma unroll
            for (int i = 0; i < 4; ++i)
#pragma unroll
                for (int j = 0; j < 2; ++j) {
                    if (ks == 0) {
                        sacc0[i][j] = mfma16(a[i], qf0[0][j], z4);
                        sacc1[i][j] = mfma16(a[i], qf1[0][j], z4);
                    } else {
                        sacc0[i][j] = mfma16(a[i], qf0[1][j], sacc0[i][j]);
                        sacc1[i][j] = mfma16(a[i], qf1[1][j], sacc1[i][j]);
                    }
                }
        }
        __builtin_amdgcn_s_setprio(0);

        // ---- issue V-frag loads now; L2 latency hides under exp/pack ----
        // B-operand: lane l15 = d-col, elements = tokens ks*32+quad*8..
        f16x8 bf[2][4];
#pragma unroll
        for (int ks = 0; ks < 2; ++ks)
#pragma unroll
            for (int j = 0; j < 4; ++j)
                bf[ks][j] = *(const f16x8*)&vkt[(long)(j * 16 + l15) * 8192 + ks * 32 + quad * 8];

        // ---- exp + rowsum + pack -> Ps0/Ps1 (wave-private rows) ----
#pragma unroll
        for (int i = 0; i < 4; ++i) {
#pragma unroll
            for (int j = 0; j < 2; ++j) {
                int qrow = w * 32 + j * 16 + l15;
                int kl = i * 16 + quad * 4;
                int c = kl >> 3;
                int off = qrow * 64 + ((c ^ (qrow & 7)) << 3) + (kl & 7);
                {
                    float p0 = __builtin_amdgcn_exp2f(sacc0[i][j][0]);
                    float p1 = __builtin_amdgcn_exp2f(sacc0[i][j][1]);
                    float p2 = __builtin_amdgcn_exp2f(sacc0[i][j][2]);
                    float p3 = __builtin_amdgcn_exp2f(sacc0[i][j][3]);
                    rs0[j] += (p0 + p1) + (p2 + p3);
                    f16x2 lo = __builtin_bit_cast(f16x2, __builtin_amdgcn_cvt_pkrtz(p0, p1));
                    f16x2 hi = __builtin_bit_cast(f16x2, __builtin_amdgcn_cvt_pkrtz(p2, p3));
                    f16x4 ph;
                    ph[0] = lo[0]; ph[1] = lo[1]; ph[2] = hi[0]; ph[3] = hi[1];
                    *(f16x4*)&Ps0[off] = ph;
                }
                {
                    float p0 = __builtin_amdgcn_exp2f(sacc1[i][j][0]);
                    float p1 = __builtin_amdgcn_exp2f(sacc1[i][j][1]);
                    float p2 = __builtin_amdgcn_exp2f(sacc1[i][j][2]);
                    float p3 = __builtin_amdgcn_exp2f(sacc1[i][j][3]);
                    rs1[j] += (p0 + p1) + (p2 + p3);
                    f16x2 lo = __builtin_bit_cast(f16x2, __builtin_amdgcn_cvt_pkrtz(p0, p1));
                    f16x2 hi = __builtin_bit_cast(f16x2, __builtin_amdgcn_cvt_pkrtz(p2, p3));
                    f16x4 ph;
                    ph[0] = lo[0]; ph[1] = lo[1]; ph[2] = hi[0]; ph[3] = hi[1];
                    *(f16x4*)&Ps1[off] = ph;
                }
            }
        }

        // ---- PV: P from LDS (same-wave in-order), V frags already in regs ----
        __builtin_amdgcn_s_setprio(1);
#pragma unroll
        for (int ks = 0; ks < 2; ++ks) {
            int cc = (ks * 4 + quad) ^ (l15 & 7);
            f16x8 af0[2], af1[2];
#pragma unroll
            for (int i = 0; i < 2; ++i) {
                af0[i] = *(const f16x8*)&Ps0[(w * 32 + i * 16 + l15) * 64 + cc * 8];
                af1[i] = *(const f16x8*)&Ps1[(w * 32 + i * 16 + l15) * 64 + cc * 8];
            }
#pragma unroll
            for (int i = 0; i < 2; ++i)
#pragma unroll
                for (int j = 0; j < 4; ++j) {
                    oacc0[i][j] = mfma16(af0[i], bf[ks][j], oacc0[i][j]);
                    oacc1[i][j] = mfma16(af1[i], bf[ks][j], oacc1[i][j]);
                }
        }
        __builtin_amdgcn_s_setprio(0);

        kkt += 64 * 1024;
        vkt += 64;
    }

    // rowsum reduction across quads. lw = this wave's own 4KB region of Ps0
    // (rows w*32..): write lane<16, read all lanes -- same-wave in-order DS,
    // no barrier needed (pattern proven in v3).
    float* lw = (float*)&Ps0[(w * 32) * 64];  // 64 floats used
#pragma unroll
    for (int j = 0; j < 2; ++j) {
        rs0[j] += __shfl_xor(rs0[j], 16, 64);
        rs0[j] += __shfl_xor(rs0[j], 32, 64);
        rs1[j] += __shfl_xor(rs1[j], 16, 64);
        rs1[j] += __shfl_xor(rs1[j], 32, 64);
    }
    if (lane < 16) {
        lw[lane] = 1.0f / rs0[0];
        lw[16 + lane] = 1.0f / rs0[1];
        lw[32 + lane] = 1.0f / rs1[0];
        lw[48 + lane] = 1.0f / rs1[1];
    }

    long otok = tok0 + qrow0;
#pragma unroll
    for (int i = 0; i < 2; ++i) {
        int lrow = i * 16 + quad * 4;          // local row within wave's 32
        int qrow = w * 32 + lrow;
#pragma unroll
        for (int j = 0; j < 4; ++j) {
            int d = j * 16 + l15;
#pragma unroll
            for (int r = 0; r < 4; ++r) {
                Op[(otok + qrow + r) * 1024 + h * 64 + d] =
                    (f16)(oacc0[i][j][r] * lw[lrow + r]);
                Op[(otok + 128 + qrow + r) * 1024 + h * 64 + d] =
                    (f16)(oacc1[i][j][r] * lw[32 + lrow + r]);
            }
        }
    }
}

// Fused fp32->fp16 conversion: q,k,v (8.4M elems each) + 4 weights (1M each).
__global__ void cvt_all(const float* __restrict__ q, const float* __restrict__ k,
                        const float* __restrict__ v, const float* __restrict__ w0,
                        const float* __restrict__ w1, const float* __restrict__ w2,
                        const float* __restrict__ w3, f16* __restrict__ qh,
                        f16* __restrict__ kh, f16* __restrict__ vh,
                        f16* __restrict__ wh) {
    long id = (long)blockIdx.x * 256 + threadIdx.x;  // 3,670,016 total
    const float* s;
    f16* d;
    long off;
    if (id < 3145728) {
        int which = (int)(id >> 20);
        off = (id & 1048575) * 8;
        s = which == 0 ? q : which == 1 ? k : v;
        d = which == 0 ? qh : which == 1 ? kh : vh;
    } else {
        long id2 = id - 3145728;
        int wi = (int)(id2 >> 17);
        off = (id2 & 131071) * 8;
        s = wi == 0 ? w0 : wi == 1 ? w1 : wi == 2 ? w2 : w3;
        d = wh + (long)wi * 1048576;
    }
    f32x4 a = *(const f32x4*)(s + off);
    f32x4 b = *(const f32x4*)(s + off + 4);
    f16x8 hv;
    hv[0] = (f16)a[0]; hv[1] = (f16)a[1]; hv[2] = (f16)a[2]; hv[3] = (f16)a[3];
    hv[4] = (f16)b[0]; hv[5] = (f16)b[1]; hv[6] = (f16)b[2]; hv[7] = (f16)b[3];
    *(f16x8*)(d + off) = hv;
}

extern "C" void kernel_launch(void* const* d_in, const int* in_sizes, int n_in,
                              void* d_out, int out_size, void* d_ws, size_t ws_size,
                              hipStream_t stream) {
    const float* q  = (const float*)d_in[0];
    const float* k  = (const float*)d_in[1];
    const float* v  = (const float*)d_in[2];
    // d_in[3] padding_mask, d_in[4] sequence_mask: no effect in reference
    const float* Wq = (const float*)d_in[5];
    const float* bq = (const float*)d_in[6];
    const float* Wk = (const float*)d_in[7];
    const float* bk = (const float*)d_in[8];
    const float* Wv = (const float*)d_in[9];
    const float* bv = (const float*)d_in[10];
    const float* Wo = (const float*)d_in[11];
    const float* bo = (const float*)d_in[12];

    // 120 MB workspace, race-free across the merged qkv launch:
    //   qh [  0, 16MB)   kh [ 16, 32MB)   vh [ 32, 48MB)   Wh [ 48, 56MB)
    //   Qp [ 56, 72MB)   Kp [ 72, 88MB)   Vt [ 88,104MB)   Op [104,120MB)
    char* ws = (char*)d_ws;
    f16* qh = (f16*)ws;
    f16* kh = (f16*)(ws + (16L << 20));
    f16* vh = (f16*)(ws + (32L << 20));
    f16* Wh = (f16*)(ws + (48L << 20));
    f16* Qp = (f16*)(ws + (56L << 20));
    f16* Kp = (f16*)(ws + (72L << 20));
    f16* Vt = (f16*)(ws + (88L << 20));
    f16* Op = (f16*)(ws + (104L << 20));

    cvt_all<<<14336, 256, 0, stream>>>(q, k, v, Wq, Wk, Wv, Wo, qh, kh, vh, Wh);

    qkv_proj<<<dim3(64, 8, 3), 256, 0, stream>>>(qh, kh, vh, Wh, bq, bk, bv,
                                                 Qp, Kp, Vt);

    attn256<<<512, 256, 0, stream>>>(Qp, Kp, Vt, Op);

    o_proj<<<dim3(64, 8), 256, 0, stream>>>(Op, Wh + 3145728, bo, (float*)d_out);
}

// Round 5
// 340.487 us; speedup vs baseline: 1.1399x; 1.1399x over previous
//
#include <hip/hip_runtime.h>
#include <stdint.h>

typedef _Float16 f16;
typedef _Float16 f16x8 __attribute__((ext_vector_type(8)));
typedef _Float16 f16x4 __attribute__((ext_vector_type(4)));
typedef _Float16 f16x2 __attribute__((ext_vector_type(2)));
typedef float f32x4 __attribute__((ext_vector_type(4)));

__device__ __forceinline__ f32x4 mfma16(f16x8 a, f16x8 b, f32x4 c) {
    return __builtin_amdgcn_mfma_f32_16x16x32_f16(a, b, c, 0, 0, 0);
}

// Async global->LDS, 16B per lane. LDS dest = wave-uniform base + lane*16.
__device__ __forceinline__ void gload16(const f16* g, f16* l) {
    __builtin_amdgcn_global_load_lds(
        (const __attribute__((address_space(1))) uint32_t*)g,
        (__attribute__((address_space(3))) uint32_t*)l, 16, 0, 0);
}

// ---------------------------------------------------------------------------
// Shared GEMM body v3: C[m][n] = (sum_k A[m*1024+k]*B[n*1024+k]+bias)*scale.
// K=1024. 128x128 tile, 4 waves 2x2, 16x16x32 f16 MFMA.
// T4 counted-vmcnt pipeline: BK=32, THREE k-tile buffers (3 x 16KB = 48KB
// -> 3 blocks/CU, qkv 1536 blocks = exactly 2 residency rounds). Per iter:
// issue stage for tile k+2, ds_read+16 MFMA on tile k, then
// s_waitcnt vmcnt(4) (retires tile k+1's 4 loads, leaves k+2's in flight)
// + raw s_barrier. The vmcnt(0)-drain-every-iter of the old structure is
// gone; loads span two compute phases. Round-1's dbuf failed by dropping
// occupancy (64KB); this keeps 3 blocks/CU AND pipelines.
// LDS row = 32 f16, 4 chunks of 8. Store chunk swizzle (lane&3)^((lane>>3)&3),
// read chunk quad^((l15>>1)&3): any 8 consecutive lanes cover all 8 bank
// positions (2 row-parities x 4 chunks); read k-slice = quad*8 for both A
// and B fragments (swizzles cancel), matching the MFMA operand layout.
// ---------------------------------------------------------------------------
template <bool OUT16>
__device__ __forceinline__ void gemm_body(const f16* __restrict__ A,
                                          const f16* __restrict__ B,
                                          const float* __restrict__ bias,
                                          void* __restrict__ Cout, long ldo,
                                          int biasrow, float scale,
                                          long m0, long n0, f16* As, f16* Bs) {
    int tid = threadIdx.x;
    int lane = tid & 63, w = tid >> 6;
    int wm = w & 1, wn = w >> 1;
    int l15 = lane & 15, quad = lane >> 4;

    int r4 = lane >> 2;                        // row within 16-row group
    int c4 = (lane & 3) ^ ((lane >> 3) & 3);   // swizzled src chunk
    const f16* ag[2];
    const f16* bg[2];
    int off[2];
#pragma unroll
    for (int t = 0; t < 2; ++t) {
        int rb = t * 64 + w * 16;
        ag[t] = A + (m0 + rb + r4) * 1024 + c4 * 8;
        bg[t] = B + (n0 + rb + r4) * 1024 + c4 * 8;
        off[t] = rb * 32;
    }

    f32x4 acc[4][4] = {};

    // prologue: stage k-tiles 0,1 into slots 0,1 (tile0 oldest)
#pragma unroll
    for (int t = 0; t < 2; ++t) {
        gload16(ag[t], &As[off[t]]);
        gload16(bg[t], &Bs[off[t]]);
    }
#pragma unroll
    for (int t = 0; t < 2; ++t) {
        gload16(ag[t] + 32, &As[4096 + off[t]]);
        gload16(bg[t] + 32, &Bs[4096 + off[t]]);
    }
    asm volatile("s_waitcnt vmcnt(4)" ::: "memory");  // tile0 done, tile1 flying
    __builtin_amdgcn_s_barrier();
    __builtin_amdgcn_sched_barrier(0);

    int cur = 0;
    for (int kt = 0; kt < 32; ++kt) {
        // issue stage for tile kt+2 into slot (cur+2)%3 (= buffer computed
        // last iter, reads fenced by last barrier)
        if (kt < 30) {
            int slot = (cur == 0) ? 2 : cur - 1;
            const int ko = (kt + 2) * 32;
#pragma unroll
            for (int t = 0; t < 2; ++t) {
                gload16(ag[t] + ko, &As[slot * 4096 + off[t]]);
                gload16(bg[t] + ko, &Bs[slot * 4096 + off[t]]);
            }
        }
        const f16* as = As + cur * 4096;
        const f16* bs = Bs + cur * 4096;
        int cs = (quad ^ ((l15 >> 1) & 3)) * 8;
        f16x8 af[4], bf[4];
#pragma unroll
        for (int t = 0; t < 4; ++t) {
            af[t] = *(const f16x8*)&as[(wm * 64 + t * 16 + l15) * 32 + cs];
            bf[t] = *(const f16x8*)&bs[(wn * 64 + t * 16 + l15) * 32 + cs];
        }
#pragma unroll
        for (int i = 0; i < 4; ++i)
#pragma unroll
            for (int j = 0; j < 4; ++j)
                acc[i][j] = mfma16(af[i], bf[j], acc[i][j]);
        if (kt < 31) {
            if (kt < 30)
                asm volatile("s_waitcnt vmcnt(4)" ::: "memory");
            else
                asm volatile("s_waitcnt vmcnt(0)" ::: "memory");
            __builtin_amdgcn_s_barrier();
            __builtin_amdgcn_sched_barrier(0);
        }
        cur = (cur == 2) ? 0 : cur + 1;
    }

    // C/D layout: col = lane&15, row = quad*4 + reg
#pragma unroll
    for (int i = 0; i < 4; ++i) {
        int mrow = wm * 64 + i * 16 + quad * 4;
#pragma unroll
        for (int j = 0; j < 4; ++j) {
            int ncol = wn * 64 + j * 16 + l15;
            long gn = n0 + ncol;
#pragma unroll
            for (int r = 0; r < 4; ++r) {
                long gm = m0 + mrow + r;
                float v = (acc[i][j][r] + (biasrow ? bias[gm] : bias[gn])) * scale;
                if constexpr (OUT16)
                    ((f16*)Cout)[gm * ldo + gn] = (f16)v;
                else
                    ((float*)Cout)[gm * ldo + gn] = v;
            }
        }
    }
}

// Merged Q/K/V projection: grid (64, 8, 3); z selects operand set.
// z=0: Qp = (q@Wq^T+bq)*log2e/32  (softmax scale folded -> attn uses exp2)
// z=1: Kp = k@Wk^T+bk
// z=2: Vt = (v@Wv^T+bv)^T  computed as Wv x v^T -> [e][tok], bias per row
__global__ __launch_bounds__(256, 2) void qkv_proj(
    const f16* __restrict__ qh, const f16* __restrict__ kh,
    const f16* __restrict__ vh, const f16* __restrict__ Wh,
    const float* __restrict__ bq, const float* __restrict__ bk,
    const float* __restrict__ bv, f16* __restrict__ Qp, f16* __restrict__ Kp,
    f16* __restrict__ Vt) {
    __shared__ __align__(16) f16 As[3 * 128 * 32];
    __shared__ __align__(16) f16 Bs[3 * 128 * 32];
    int z = blockIdx.z;
    const f16* A;
    const f16* B;
    const float* bias;
    f16* C;
    long ldo;
    int biasrow;
    float scale;
    if (z == 0) {
        A = qh; B = Wh; bias = bq; C = Qp; ldo = 1024; biasrow = 0;
        scale = 0.0450842200277786f;  // log2(e)/32
    } else if (z == 1) {
        A = kh; B = Wh + 1048576; bias = bk; C = Kp; ldo = 1024; biasrow = 0;
        scale = 1.0f;
    } else {
        A = Wh + 2097152; B = vh; bias = bv; C = Vt; ldo = 8192; biasrow = 1;
        scale = 1.0f;
    }
    long m0 = (long)(z == 2 ? blockIdx.y : blockIdx.x) * 128;
    long n0 = (long)(z == 2 ? blockIdx.x : blockIdx.y) * 128;
    gemm_body<true>(A, B, bias, C, ldo, biasrow, scale, m0, n0, As, Bs);
}

// Output projection: out = Op@Wo^T + bo (fp32 out)
__global__ __launch_bounds__(256, 2) void o_proj(const f16* __restrict__ Op,
                                                 const f16* __restrict__ Wo,
                                                 const float* __restrict__ bo,
                                                 float* __restrict__ out) {
    __shared__ __align__(16) f16 As[3 * 128 * 32];
    __shared__ __align__(16) f16 Bs[3 * 128 * 32];
    gemm_body<false>(Op, Wo, bo, out, 1024, 0, 1.0f, (long)blockIdx.x * 128,
                     (long)blockIdx.y * 128, As, Bs);
}

// ---------------------------------------------------------------------------
// Attention v7: v3 body (proven 91us: 512 blocks, 256-row q-pair, K/V tiles
// shared by both q-tiles, single barrier/kt) with the drain removed:
// K/V TRIPLE-buffered (LDS 80KB -> still 2 blocks/CU), prefetch tile kt+2,
// and the per-kt __syncthreads (vmcnt(0)+lgkmcnt(0) drain) replaced by
// s_waitcnt vmcnt(4) + raw s_barrier: tile k+1's 4 loads retired, tile
// k+2's stay in flight across the barrier (T4). vmcnt(0) only at kt=30.
// P ds_writes are wave-private rows -> no lgkm drain needed at barriers.
// Round-4 lesson kept: K/V MUST be LDS-staged (one fetch per block-tile);
// per-wave L2 reads quadrupled traffic and regressed 50%.
// ---------------------------------------------------------------------------
__global__ __launch_bounds__(256, 2) void attn256(const f16* __restrict__ Qp,
                                                  const f16* __restrict__ Kp,
                                                  const f16* __restrict__ Vt,
                                                  f16* __restrict__ Op) {
    __shared__ __align__(16) f16 Ps0[128 * 64];
    __shared__ __align__(16) f16 Ps1[128 * 64];
    __shared__ __align__(16) f16 Ks[3][64 * 64];
    __shared__ __align__(16) f16 Vs[3][64 * 64];

    int tid = threadIdx.x;
    int lane = tid & 63, w = tid >> 6;
    int l15 = lane & 15, quad = lane >> 4;
    int b = blockIdx.x;
    int xcd = b & 7, slot = b >> 3;        // 64 slots per XCD
    int nh = xcd * 8 + (slot >> 3);        // 8 (n,h) per XCD
    int qp = slot & 7;                     // 8 q-pairs per (n,h)
    int nb = nh >> 4, h = nh & 15;
    long tok0 = (long)nb * 2048;
    long qrow0 = qp * 256;

    int rg = lane >> 3, cg = (lane & 7) ^ rg;

    // stage both Q tiles FIRST (oldest vmcnt entries; wave-private rows)
    const f16* qsrc0 = Qp + (tok0 + qrow0) * 1024 + h * 64;
    const f16* qsrc1 = qsrc0 + 128 * 1024;
#pragma unroll
    for (int t = 0; t < 4; ++t) {
        int rb = w * 32 + t * 8;
        gload16(qsrc0 + (rb + rg) * 1024 + cg * 8, &Ps0[rb * 64]);
        gload16(qsrc1 + (rb + rg) * 1024 + cg * 8, &Ps1[rb * 64]);
    }
    // K/V tiles 0 and 1
    const f16* kptr = Kp + (tok0 + w * 16 + rg) * 1024 + h * 64 + cg * 8;
    const f16* vptr = Vt + ((long)h * 64 + w * 16 + rg) * 8192 + tok0 + cg * 8;
    gload16(kptr, &Ks[0][(w * 16) * 64]);
    gload16(kptr + 8 * 1024, &Ks[0][(w * 16 + 8) * 64]);
    gload16(vptr, &Vs[0][(w * 16) * 64]);
    gload16(vptr + (long)8 * 8192, &Vs[0][(w * 16 + 8) * 64]);
    gload16(kptr + 65536, &Ks[1][(w * 16) * 64]);
    gload16(kptr + 65536 + 8 * 1024, &Ks[1][(w * 16 + 8) * 64]);
    gload16(vptr + 64, &Vs[1][(w * 16) * 64]);
    gload16(vptr + 64 + (long)8 * 8192, &Vs[1][(w * 16 + 8) * 64]);
    const f16* kn = kptr + 2 * 65536;
    const f16* vn = vptr + 2 * 64;

    // hoist Q fragments: own-wave Q loads are the 8 oldest -> vmcnt(8);
    // rows are wave-private so no barrier needed before the reads
    asm volatile("s_waitcnt vmcnt(8)" ::: "memory");
    f16x8 qf0[2][2], qf1[2][2];
#pragma unroll
    for (int ks = 0; ks < 2; ++ks) {
        int cc = (ks * 4 + quad) ^ (l15 & 7);
#pragma unroll
        for (int j = 0; j < 2; ++j) {
            qf0[ks][j] = *(const f16x8*)&Ps0[(w * 32 + j * 16 + l15) * 64 + cc * 8];
            qf1[ks][j] = *(const f16x8*)&Ps1[(w * 32 + j * 16 + l15) * 64 + cc * 8];
        }
    }
    // K/V tile0 complete (cross-wave), tile1 left in flight
    asm volatile("s_waitcnt vmcnt(4)" ::: "memory");
    __builtin_amdgcn_s_barrier();
    __builtin_amdgcn_sched_barrier(0);

    f32x4 oacc0[2][4] = {}, oacc1[2][4] = {};
    float rs0[2] = {0.f, 0.f}, rs1[2] = {0.f, 0.f};
    const f32x4 z4 = {0.f, 0.f, 0.f, 0.f};

    int cur = 0;
    for (int kt = 0; kt < 32; ++kt) {
        // S tiles: K fragments read ONCE, feed both q-tiles
        f32x4 sacc0[4][2], sacc1[4][2];
        __builtin_amdgcn_s_setprio(1);
#pragma unroll
        for (int ks = 0; ks < 2; ++ks) {
            int cc = (ks * 4 + quad) ^ (l15 & 7);
            f16x8 a[4];
#pragma unroll
            for (int t = 0; t < 4; ++t)
                a[t] = *(const f16x8*)&Ks[cur][(t * 16 + l15) * 64 + cc * 8];
#pragma unroll
            for (int i = 0; i < 4; ++i)
#pragma unroll
                for (int j = 0; j < 2; ++j) {
                    if (ks == 0) {
                        sacc0[i][j] = mfma16(a[i], qf0[0][j], z4);
                        sacc1[i][j] = mfma16(a[i], qf1[0][j], z4);
                    } else {
                        sacc0[i][j] = mfma16(a[i], qf0[1][j], sacc0[i][j]);
                        sacc1[i][j] = mfma16(a[i], qf1[1][j], sacc1[i][j]);
                    }
                }
        }
        __builtin_amdgcn_s_setprio(0);
        // async prefetch tile kt+2 into slot (cur+2)%3 (read-fenced last iter)
        if (kt < 30) {
            int nxt = (cur == 0) ? 2 : cur - 1;
            f16* kd = &Ks[nxt][(w * 16) * 64];
            f16* vd = &Vs[nxt][(w * 16) * 64];
            gload16(kn, kd);
            gload16(kn + 8 * 1024, kd + 8 * 64);
            gload16(vn, vd);
            gload16(vn + (long)8 * 8192, vd + 8 * 64);
            kn += 65536;
            vn += 64;
        }
        // exp + rowsum + pack for both tiles (wave-private rows)
#pragma unroll
        for (int i = 0; i < 4; ++i) {
#pragma unroll
            for (int j = 0; j < 2; ++j) {
                int qrow = w * 32 + j * 16 + l15;
                int kl = i * 16 + quad * 4;
                int c = kl >> 3;
                int off = qrow * 64 + ((c ^ (qrow & 7)) << 3) + (kl & 7);
                {
                    float p0 = __builtin_amdgcn_exp2f(sacc0[i][j][0]);
                    float p1 = __builtin_amdgcn_exp2f(sacc0[i][j][1]);
                    float p2 = __builtin_amdgcn_exp2f(sacc0[i][j][2]);
                    float p3 = __builtin_amdgcn_exp2f(sacc0[i][j][3]);
                    rs0[j] += (p0 + p1) + (p2 + p3);
                    f16x2 lo = __builtin_bit_cast(f16x2, __builtin_amdgcn_cvt_pkrtz(p0, p1));
                    f16x2 hi = __builtin_bit_cast(f16x2, __builtin_amdgcn_cvt_pkrtz(p2, p3));
                    f16x4 ph;
                    ph[0] = lo[0]; ph[1] = lo[1]; ph[2] = hi[0]; ph[3] = hi[1];
                    *(f16x4*)&Ps0[off] = ph;
                }
                {
                    float p0 = __builtin_amdgcn_exp2f(sacc1[i][j][0]);
                    float p1 = __builtin_amdgcn_exp2f(sacc1[i][j][1]);
                    float p2 = __builtin_amdgcn_exp2f(sacc1[i][j][2]);
                    float p3 = __builtin_amdgcn_exp2f(sacc1[i][j][3]);
                    rs1[j] += (p0 + p1) + (p2 + p3);
                    f16x2 lo = __builtin_bit_cast(f16x2, __builtin_amdgcn_cvt_pkrtz(p0, p1));
                    f16x2 hi = __builtin_bit_cast(f16x2, __builtin_amdgcn_cvt_pkrtz(p2, p3));
                    f16x4 ph;
                    ph[0] = lo[0]; ph[1] = lo[1]; ph[2] = hi[0]; ph[3] = hi[1];
                    *(f16x4*)&Ps1[off] = ph;
                }
            }
        }
        // PV: V fragments read ONCE, feed both q-tiles
        __builtin_amdgcn_s_setprio(1);
#pragma unroll
        for (int ks = 0; ks < 2; ++ks) {
            int cc = (ks * 4 + quad) ^ (l15 & 7);
            f16x8 bf[4];
#pragma unroll
            for (int j = 0; j < 4; ++j)
                bf[j] = *(const f16x8*)&Vs[cur][(j * 16 + l15) * 64 + cc * 8];
            f16x8 af0[2], af1[2];
#pragma unroll
            for (int i = 0; i < 2; ++i) {
                af0[i] = *(const f16x8*)&Ps0[(w * 32 + i * 16 + l15) * 64 + cc * 8];
                af1[i] = *(const f16x8*)&Ps1[(w * 32 + i * 16 + l15) * 64 + cc * 8];
            }
#pragma unroll
            for (int i = 0; i < 2; ++i)
#pragma unroll
                for (int j = 0; j < 4; ++j) {
                    oacc0[i][j] = mfma16(af0[i], bf[ks * 0 + j], oacc0[i][j]);
                    oacc1[i][j] = mfma16(af1[i], bf[j], oacc1[i][j]);
                }
        }
        __builtin_amdgcn_s_setprio(0);
        // counted-vmcnt barrier: tile kt+1 retired, tile kt+2 stays in flight
        if (kt < 31) {
            if (kt < 30)
                asm volatile("s_waitcnt vmcnt(4)" ::: "memory");
            else
                asm volatile("s_waitcnt vmcnt(0)" ::: "memory");
            __builtin_amdgcn_s_barrier();
            __builtin_amdgcn_sched_barrier(0);
        }
        cur = (cur == 2) ? 0 : cur + 1;
    }

    // rowsum reduction across quads; lsi aliases Ks[0] (last read kt=30,
    // fenced by that barrier; writes/reads are wave-private rows)
    float* lsi = (float*)&Ks[0][0];  // 256 floats
#pragma unroll
    for (int j = 0; j < 2; ++j) {
        rs0[j] += __shfl_xor(rs0[j], 16, 64);
        rs0[j] += __shfl_xor(rs0[j], 32, 64);
        rs1[j] += __shfl_xor(rs1[j], 16, 64);
        rs1[j] += __shfl_xor(rs1[j], 32, 64);
    }
    if (lane < 16) {
        lsi[w * 32 + lane] = 1.0f / rs0[0];
        lsi[w * 32 + 16 + lane] = 1.0f / rs0[1];
        lsi[128 + w * 32 + lane] = 1.0f / rs1[0];
        lsi[128 + w * 32 + 16 + lane] = 1.0f / rs1[1];
    }

    long otok = tok0 + qrow0;
#pragma unroll
    for (int i = 0; i < 2; ++i) {
        int qrow = w * 32 + i * 16 + quad * 4;
#pragma unroll
        for (int j = 0; j < 4; ++j) {
            int d = j * 16 + l15;
#pragma unroll
            for (int r = 0; r < 4; ++r) {
                Op[(otok + qrow + r) * 1024 + h * 64 + d] =
                    (f16)(oacc0[i][j][r] * lsi[qrow + r]);
                Op[(otok + 128 + qrow + r) * 1024 + h * 64 + d] =
                    (f16)(oacc1[i][j][r] * lsi[128 + qrow + r]);
            }
        }
    }
}

// Fused fp32->fp16 conversion: q,k,v (8.4M elems each) + 4 weights (1M each).
__global__ void cvt_all(const float* __restrict__ q, const float* __restrict__ k,
                        const float* __restrict__ v, const float* __restrict__ w0,
                        const float* __restrict__ w1, const float* __restrict__ w2,
                        const float* __restrict__ w3, f16* __restrict__ qh,
                        f16* __restrict__ kh, f16* __restrict__ vh,
                        f16* __restrict__ wh) {
    long id = (long)blockIdx.x * 256 + threadIdx.x;  // 3,670,016 total
    const float* s;
    f16* d;
    long off;
    if (id < 3145728) {
        int which = (int)(id >> 20);
        off = (id & 1048575) * 8;
        s = which == 0 ? q : which == 1 ? k : v;
        d = which == 0 ? qh : which == 1 ? kh : vh;
    } else {
        long id2 = id - 3145728;
        int wi = (int)(id2 >> 17);
        off = (id2 & 131071) * 8;
        s = wi == 0 ? w0 : wi == 1 ? w1 : wi == 2 ? w2 : w3;
        d = wh + (long)wi * 1048576;
    }
    f32x4 a = *(const f32x4*)(s + off);
    f32x4 b = *(const f32x4*)(s + off + 4);
    f16x8 hv;
    hv[0] = (f16)a[0]; hv[1] = (f16)a[1]; hv[2] = (f16)a[2]; hv[3] = (f16)a[3];
    hv[4] = (f16)b[0]; hv[5] = (f16)b[1]; hv[6] = (f16)b[2]; hv[7] = (f16)b[3];
    *(f16x8*)(d + off) = hv;
}

extern "C" void kernel_launch(void* const* d_in, const int* in_sizes, int n_in,
                              void* d_out, int out_size, void* d_ws, size_t ws_size,
                              hipStream_t stream) {
    const float* q  = (const float*)d_in[0];
    const float* k  = (const float*)d_in[1];
    const float* v  = (const float*)d_in[2];
    // d_in[3] padding_mask, d_in[4] sequence_mask: no effect in reference
    const float* Wq = (const float*)d_in[5];
    const float* bq = (const float*)d_in[6];
    const float* Wk = (const float*)d_in[7];
    const float* bk = (const float*)d_in[8];
    const float* Wv = (const float*)d_in[9];
    const float* bv = (const float*)d_in[10];
    const float* Wo = (const float*)d_in[11];
    const float* bo = (const float*)d_in[12];

    // 120 MB workspace, race-free across the merged qkv launch:
    //   qh [  0, 16MB)   kh [ 16, 32MB)   vh [ 32, 48MB)   Wh [ 48, 56MB)
    //   Qp [ 56, 72MB)   Kp [ 72, 88MB)   Vt [ 88,104MB)   Op [104,120MB)
    char* ws = (char*)d_ws;
    f16* qh = (f16*)ws;
    f16* kh = (f16*)(ws + (16L << 20));
    f16* vh = (f16*)(ws + (32L << 20));
    f16* Wh = (f16*)(ws + (48L << 20));
    f16* Qp = (f16*)(ws + (56L << 20));
    f16* Kp = (f16*)(ws + (72L << 20));
    f16* Vt = (f16*)(ws + (88L << 20));
    f16* Op = (f16*)(ws + (104L << 20));

    cvt_all<<<14336, 256, 0, stream>>>(q, k, v, Wq, Wk, Wv, Wo, qh, kh, vh, Wh);

    qkv_proj<<<dim3(64, 8, 3), 256, 0, stream>>>(qh, kh, vh, Wh, bq, bk, bv,
                                                 Qp, Kp, Vt);

    attn256<<<512, 256, 0, stream>>>(Qp, Kp, Vt, Op);

    o_proj<<<dim3(64, 8), 256, 0, stream>>>(Op, Wh + 3145728, bo, (float*)d_out);
}